// Round 3
// baseline (334.204 us; speedup 1.0000x reference)
//
#include <hip/hip_runtime.h>
#include <math.h>

#define DIM  64
#define KN   16
#define NREL 32

__device__ __forceinline__ float frcp(float x) { return __builtin_amdgcn_rcpf(x); }

// Block = 1024 threads = 16 waves = ONE pair. Wave w owns hop-1 group w.
// One barrier; wave 0 runs the hop-0 tail. 65536 phase-A waves across the
// device -> full 8-waves/SIMD residency hides gather latency by TLP.
__global__ __launch_bounds__(1024, 8) void kgcn_kernel(
    const int* __restrict__ pairs,
    const int* __restrict__ adj_entity,
    const int* __restrict__ adj_relation,
    const float* __restrict__ entity_emb,
    const float* __restrict__ relation_emb,
    const float* __restrict__ user_emb,
    const float* __restrict__ W,
    const float* __restrict__ bias,
    float* __restrict__ out)
{
    __shared__ float ev1[KN * DIM];   // layer-0 outputs of the 16 groups
    __shared__ float xb[KN][DIM];     // per-wave matvec broadcast buffers

    const int tid  = threadIdx.x;
    const int wave = tid >> 6;
    const int lane = tid & 63;
    const int p    = blockIdx.x;

    const int user = pairs[2 * p + 0];
    const int item = pairs[2 * p + 1];

    const float bval   = bias[lane];
    const float* emb_l = entity_emb + lane;
    const float4* W4   = (const float4*)(W + lane * DIM);  // lane's W row (L1-hot)

    // this wave's hop-1 group id (same addr across lanes -> broadcast load)
    const int g = adj_entity[(size_t)item * KN + wave];

    // adjacency rows: this group's (rk, ek) and the item's (rk0, e1)
    int rk = 0, ek = 0, rk0 = 0, e1 = 0;
    if (lane < KN) {
        rk  = adj_relation[(size_t)(unsigned)g * KN + lane];
        ek  = adj_entity  [(size_t)(unsigned)g * KN + lane];
        rk0 = adj_relation[(size_t)item * KN + lane];
        e1  = adj_entity  [(size_t)item * KN + lane];
    }

    // ---- dot(u, rel_r) for ALL 32 relations: 2 lanes per relation ----
    float acc;
    {
        const int r = lane >> 1, half = lane & 1;
        const float4* rel4 = (const float4*)(relation_emb + r * DIM + half * 32);
        const float4* u4   = (const float4*)(user_emb + (size_t)user * DIM + half * 32);
        acc = 0.f;
        #pragma unroll
        for (int j = 0; j < 8; ++j) {
            float4 a = rel4[j], b = u4[j];
            acc += a.x * b.x + a.y * b.y + a.z * b.z + a.w * b.w;
        }
        acc += __shfl_xor(acc, 1);   // both lanes of the pair hold the full dot
    }

    // softmax over 16 lanes, one score per lane
    auto softmax16 = [&](float s) -> float {
        float mx = s;
        mx = fmaxf(mx, __shfl_xor(mx, 1));
        mx = fmaxf(mx, __shfl_xor(mx, 2));
        mx = fmaxf(mx, __shfl_xor(mx, 4));
        mx = fmaxf(mx, __shfl_xor(mx, 8));
        float e = __expf(s - mx);
        float ss = e;
        ss += __shfl_xor(ss, 1);
        ss += __shfl_xor(ss, 2);
        ss += __shfl_xor(ss, 4);
        ss += __shfl_xor(ss, 8);
        return e * frcp(ss);
    };

    // h[lane] = b[lane] + sum_j x_j * W[lane][j]; x broadcast via LDS
    auto matvec = [&](float xv) -> float {
        asm volatile("s_waitcnt lgkmcnt(0)" ::: "memory");  // WAR vs prior xb reads
        xb[wave][lane] = xv;
        asm volatile("s_waitcnt lgkmcnt(0)" ::: "memory");  // write visible to wave
        float h = bval;
        const float4* xv4 = (const float4*)xb[wave];
        #pragma unroll
        for (int j = 0; j < 16; ++j) {
            float4 wv = W4[j];
            float4 xx = xv4[j];   // same addr all lanes: conflict-free broadcast
            h += wv.x * xx.x + wv.y * xx.y + wv.z * xx.z + wv.w * xx.w;
        }
        return h;
    };

    // ---- phase A: this wave's group -> attention, gather, matvec, relu ----
    const float w1 = softmax16(__shfl(acc, rk << 1));   // ds_bpermute score pickup
    float x = emb_l[(size_t)(unsigned)g * DIM];
    #pragma unroll
    for (int k = 0; k < KN; ++k) {
        const int   ekb = __shfl(ek, k);
        const float wk  = __shfl(w1, k);
        x += wk * emb_l[(size_t)(unsigned)ekb * DIM];
    }
    ev1[wave * DIM + lane] = fmaxf(matvec(x), 0.f);

    __syncthreads();
    if (wave != 0) return;

    // ---- phase B (wave 0): hop-0, layer 0 then layer 1 ----
    const float w0 = softmax16(__shfl(acc, rk0 << 1));

    float x0 = emb_l[(size_t)item * DIM];
    #pragma unroll
    for (int k = 0; k < KN; ++k) {
        const int   eb = __shfl(e1, k);
        const float wk = __shfl(w0, k);
        x0 += wk * emb_l[(size_t)(unsigned)eb * DIM];
    }
    const float e0 = fmaxf(matvec(x0), 0.f);

    float x1 = e0;
    #pragma unroll
    for (int k = 0; k < KN; ++k) {
        const float wk = __shfl(w0, k);
        x1 += wk * ev1[k * DIM + lane];
    }
    const float itemf = tanhf(matvec(x1));

    float d = user_emb[(size_t)user * DIM + lane] * itemf;
    d += __shfl_xor(d, 1);
    d += __shfl_xor(d, 2);
    d += __shfl_xor(d, 4);
    d += __shfl_xor(d, 8);
    d += __shfl_xor(d, 16);
    d += __shfl_xor(d, 32);
    if (lane == 0) out[p] = 1.f / (1.f + expf(-d));
}

extern "C" void kernel_launch(void* const* d_in, const int* in_sizes, int n_in,
                              void* d_out, int out_size, void* d_ws, size_t ws_size,
                              hipStream_t stream) {
    const int*   pairs        = (const int*)d_in[0];
    const int*   adj_entity   = (const int*)d_in[1];
    const int*   adj_relation = (const int*)d_in[2];
    const float* entity_emb   = (const float*)d_in[3];
    const float* relation_emb = (const float*)d_in[4];
    const float* user_emb     = (const float*)d_in[5];
    const float* W            = (const float*)d_in[6];
    const float* b            = (const float*)d_in[7];
    float* out = (float*)d_out;

    const int nPairs = in_sizes[0] / 2;   // pairs is (B, 2)
    kgcn_kernel<<<nPairs, 1024, 0, stream>>>(pairs, adj_entity, adj_relation,
                                             entity_emb, relation_emb, user_emb,
                                             W, b, out);
}

// Round 4
// 259.276 us; speedup vs baseline: 1.2890x; 1.2890x over previous
//
#include <hip/hip_runtime.h>
#include <math.h>

#define DIM  64
#define KN   16
#define NREL 32
#define PPB  2              // pairs per 256-thread block
#define GPW  (KN / 2)       // groups per wave = 8 (2 waves per pair)

__device__ __forceinline__ float frcp(float x) { return __builtin_amdgcn_rcpf(x); }

// Block = 256 threads = 4 waves = 2 pairs; each pair owned by 2 waves
// (8 hop-1 groups each). 8192 waves total -> 8 waves/SIMD (100% occupancy
// at <=64 VGPR) so gather latency is hidden by TLP. One barrier; the short
// hop-0 tail runs on one wave per pair (2 concurrent tails per block).
__global__ __launch_bounds__(256, 8) void kgcn_kernel(
    const int* __restrict__ pairs,
    const int* __restrict__ adj_entity,
    const int* __restrict__ adj_relation,
    const float* __restrict__ entity_emb,
    const float* __restrict__ relation_emb,
    const float* __restrict__ user_emb,
    const float* __restrict__ W,
    const float* __restrict__ bias,
    float* __restrict__ out,
    int nPairs)
{
    __shared__ float ev1_s[PPB][KN * DIM];   // layer-0 outputs, per pair
    __shared__ float xb_s[PPB * 2][DIM];     // per-wave matvec broadcast buffers

    const int tid  = threadIdx.x;
    const int wave = tid >> 6;      // 0..3
    const int lane = tid & 63;
    const int q    = wave >> 1;     // pair slot in block (0..1)
    const int half = wave & 1;      // which 8 groups this wave owns
    int p = blockIdx.x * PPB + q;
    if (p >= nPairs) p = nPairs - 1;   // defensive clamp (keeps barrier uniform)

    float* ev1 = ev1_s[q];
    float* xb  = xb_s[wave];

    const int user = pairs[2 * p + 0];
    const int item = pairs[2 * p + 1];

    const float bval   = bias[lane];
    const float* emb_l = entity_emb + lane;
    const float4* W4   = (const float4*)(W + lane * DIM);  // lane's W row, L1-hot

    // ---- item adjacency row (both waves need it) ----
    int rk0 = 0, e1 = 0;
    if (lane < KN) {
        rk0 = adj_relation[(size_t)item * KN + lane];
        e1  = adj_entity  [(size_t)item * KN + lane];
    }

    // ---- dot(u, rel_r) for all 32 relations: 2 lanes per relation ----
    float acc;
    {
        const int r = lane >> 1, hlf = lane & 1;
        const float4* rel4 = (const float4*)(relation_emb + r * DIM + hlf * 32);
        const float4* u4   = (const float4*)(user_emb + (size_t)user * DIM + hlf * 32);
        float a0 = 0.f, a1 = 0.f;
        #pragma unroll
        for (int j = 0; j < 8; j += 2) {
            float4 a = rel4[j],   b = u4[j];
            float4 c = rel4[j+1], d = u4[j+1];
            a0 += a.x*b.x + a.y*b.y + a.z*b.z + a.w*b.w;
            a1 += c.x*d.x + c.y*d.y + c.z*d.z + c.w*d.w;
        }
        acc = a0 + a1;
        acc += __shfl_xor(acc, 1);   // lanes 2r,2r+1 both hold dot(u, rel_r)
    }

    // softmax over 16 lanes, one score per lane (lanes>=16 harmless)
    auto softmax16 = [&](float s) -> float {
        float mx = s;
        mx = fmaxf(mx, __shfl_xor(mx, 1));
        mx = fmaxf(mx, __shfl_xor(mx, 2));
        mx = fmaxf(mx, __shfl_xor(mx, 4));
        mx = fmaxf(mx, __shfl_xor(mx, 8));
        float e = __expf(s - mx);
        float ss = e;
        ss += __shfl_xor(ss, 1);
        ss += __shfl_xor(ss, 2);
        ss += __shfl_xor(ss, 4);
        ss += __shfl_xor(ss, 8);
        return e * frcp(ss);
    };

    // h[lane] = b + sum_j x_j W[lane][j]; x broadcast via LDS; 4 accumulators
    auto matvec = [&](float xv) -> float {
        asm volatile("s_waitcnt lgkmcnt(0)" ::: "memory");  // WAR vs prior xb reads
        xb[lane] = xv;
        asm volatile("s_waitcnt lgkmcnt(0)" ::: "memory");  // write visible to wave
        float h0 = bval, h1 = 0.f, h2 = 0.f, h3 = 0.f;
        const float4* xv4 = (const float4*)xb;
        #pragma unroll
        for (int j = 0; j < 16; j += 4) {
            float4 w0 = W4[j],   x0 = xv4[j];
            float4 w1 = W4[j+1], x1 = xv4[j+1];
            float4 w2 = W4[j+2], x2 = xv4[j+2];
            float4 w3 = W4[j+3], x3 = xv4[j+3];
            h0 += w0.x*x0.x + w0.y*x0.y + w0.z*x0.z + w0.w*x0.w;
            h1 += w1.x*x1.x + w1.y*x1.y + w1.z*x1.z + w1.w*x1.w;
            h2 += w2.x*x2.x + w2.y*x2.y + w2.z*x2.z + w2.w*x2.w;
            h3 += w3.x*x3.x + w3.y*x3.y + w3.z*x3.z + w3.w*x3.w;
        }
        return (h0 + h1) + (h2 + h3);
    };

    // weighted gather: self + 16 neighbors, 2 accumulator chains
    auto gather = [&](int self, int ek, float w) -> float {
        float xa = emb_l[(size_t)(unsigned)self * DIM];
        float xc = 0.f;
        #pragma unroll
        for (int k = 0; k < KN; k += 2) {
            const int   e0 = __shfl(ek, k);
            const float f0 = __shfl(w,  k);
            const int   e1b = __shfl(ek, k + 1);
            const float f1 = __shfl(w,  k + 1);
            xa += f0 * emb_l[(size_t)(unsigned)e0  * DIM];
            xc += f1 * emb_l[(size_t)(unsigned)e1b * DIM];
        }
        return xa + xc;
    };

    // ---- phase A: this wave's 8 groups, adjacency prefetched 1 ahead ----
    int rk_n = 0, ek_n = 0;
    {
        const int g0 = __shfl(e1, half * GPW);
        if (lane < KN) {
            rk_n = adj_relation[(size_t)(unsigned)g0 * KN + lane];
            ek_n = adj_entity  [(size_t)(unsigned)g0 * KN + lane];
        }
    }
    #pragma unroll 1
    for (int mi = 0; mi < GPW; ++mi) {
        const int m  = half * GPW + mi;
        const int g  = __shfl(e1, m);
        const int rk = rk_n;
        const int ek = ek_n;
        if (mi + 1 < GPW) {
            const int gn = __shfl(e1, m + 1);
            if (lane < KN) {
                rk_n = adj_relation[(size_t)(unsigned)gn * KN + lane];
                ek_n = adj_entity  [(size_t)(unsigned)gn * KN + lane];
            }
        }
        const float w = softmax16(__shfl(acc, rk << 1));
        const float x = gather(g, ek, w);
        ev1[m * DIM + lane] = fmaxf(matvec(x), 0.f);
    }

    __syncthreads();
    if (half != 0) return;   // one tail wave per pair

    // ---- phase B: hop-0 layer 0 then layer 1 ----
    const float w0 = softmax16(__shfl(acc, rk0 << 1));
    const float x0 = gather(item, e1, w0);
    const float e0 = fmaxf(matvec(x0), 0.f);

    float xa = e0, xc = 0.f;
    #pragma unroll
    for (int k = 0; k < KN; k += 2) {
        xa += __shfl(w0, k)     * ev1[k * DIM + lane];
        xc += __shfl(w0, k + 1) * ev1[(k + 1) * DIM + lane];
    }
    const float itemf = tanhf(matvec(xa + xc));

    float d = user_emb[(size_t)user * DIM + lane] * itemf;
    d += __shfl_xor(d, 1);
    d += __shfl_xor(d, 2);
    d += __shfl_xor(d, 4);
    d += __shfl_xor(d, 8);
    d += __shfl_xor(d, 16);
    d += __shfl_xor(d, 32);
    if (lane == 0) out[p] = 1.f / (1.f + expf(-d));
}

extern "C" void kernel_launch(void* const* d_in, const int* in_sizes, int n_in,
                              void* d_out, int out_size, void* d_ws, size_t ws_size,
                              hipStream_t stream) {
    const int*   pairs        = (const int*)d_in[0];
    const int*   adj_entity   = (const int*)d_in[1];
    const int*   adj_relation = (const int*)d_in[2];
    const float* entity_emb   = (const float*)d_in[3];
    const float* relation_emb = (const float*)d_in[4];
    const float* user_emb     = (const float*)d_in[5];
    const float* W            = (const float*)d_in[6];
    const float* b            = (const float*)d_in[7];
    float* out = (float*)d_out;

    const int nPairs  = in_sizes[0] / 2;   // pairs is (B, 2)
    const int nBlocks = (nPairs + PPB - 1) / PPB;
    kgcn_kernel<<<nBlocks, 256, 0, stream>>>(pairs, adj_entity, adj_relation,
                                             entity_emb, relation_emb, user_emb,
                                             W, b, out, nPairs);
}

// Round 5
// 234.678 us; speedup vs baseline: 1.4241x; 1.1048x over previous
//
#include <hip/hip_runtime.h>
#include <math.h>

#define DIM  64
#define KN   16
#define NREL 32
#define PPB  2              // pairs per 256-thread block
#define GPW  (KN / 2)       // groups per wave = 8 (2 waves per pair)

__device__ __forceinline__ float frcp(float x) { return __builtin_amdgcn_rcpf(x); }

// Block = 256 threads = 4 waves = 2 pairs; each pair owned by 2 waves
// (8 hop-1 groups each). 8192 waves total -> up to 8 waves/SIMD if VGPR<=64.
// __launch_bounds__(256,4): NOT (256,8) — min-waves=8 forced a 32-VGPR
// allocation with ~100MB of scratch spill traffic in R3/R4. (256,4) gives
// the allocator room (64 VGPR, zero spills — verified in R2) while the HW
// still schedules 8 waves/SIMD when the kernel fits in 64 VGPR.
__global__ __launch_bounds__(256, 4) void kgcn_kernel(
    const int* __restrict__ pairs,
    const int* __restrict__ adj_entity,
    const int* __restrict__ adj_relation,
    const float* __restrict__ entity_emb,
    const float* __restrict__ relation_emb,
    const float* __restrict__ user_emb,
    const float* __restrict__ W,
    const float* __restrict__ bias,
    float* __restrict__ out,
    int nPairs)
{
    __shared__ float ev1_s[PPB][KN * DIM];   // layer-0 outputs, per pair
    __shared__ float xb_s[PPB * 2][DIM];     // per-wave matvec broadcast buffers

    const int tid  = threadIdx.x;
    const int wave = tid >> 6;      // 0..3
    const int lane = tid & 63;
    const int q    = wave >> 1;     // pair slot in block (0..1)
    const int half = wave & 1;      // which 8 groups this wave owns
    int p = blockIdx.x * PPB + q;
    if (p >= nPairs) p = nPairs - 1;   // defensive clamp (keeps barrier uniform)

    float* ev1 = ev1_s[q];
    float* xb  = xb_s[wave];

    const int user = pairs[2 * p + 0];
    const int item = pairs[2 * p + 1];

    const float bval   = bias[lane];
    const float* emb_l = entity_emb + lane;
    const float4* W4   = (const float4*)(W + lane * DIM);  // lane's W row, L1-hot

    // ---- item adjacency row (both waves need it) ----
    int rk0 = 0, e1 = 0;
    if (lane < KN) {
        rk0 = adj_relation[(size_t)item * KN + lane];
        e1  = adj_entity  [(size_t)item * KN + lane];
    }

    // ---- dot(u, rel_r) for all 32 relations: 2 lanes per relation ----
    float acc;
    {
        const int r = lane >> 1, hlf = lane & 1;
        const float4* rel4 = (const float4*)(relation_emb + r * DIM + hlf * 32);
        const float4* u4   = (const float4*)(user_emb + (size_t)user * DIM + hlf * 32);
        float a0 = 0.f, a1 = 0.f;
        #pragma unroll
        for (int j = 0; j < 8; j += 2) {
            float4 a = rel4[j],   b = u4[j];
            float4 c = rel4[j+1], d = u4[j+1];
            a0 += a.x*b.x + a.y*b.y + a.z*b.z + a.w*b.w;
            a1 += c.x*d.x + c.y*d.y + c.z*d.z + c.w*d.w;
        }
        acc = a0 + a1;
        acc += __shfl_xor(acc, 1);   // lanes 2r,2r+1 both hold dot(u, rel_r)
    }

    // softmax over 16 lanes, one score per lane (lanes>=16 harmless)
    auto softmax16 = [&](float s) -> float {
        float mx = s;
        mx = fmaxf(mx, __shfl_xor(mx, 1));
        mx = fmaxf(mx, __shfl_xor(mx, 2));
        mx = fmaxf(mx, __shfl_xor(mx, 4));
        mx = fmaxf(mx, __shfl_xor(mx, 8));
        float e = __expf(s - mx);
        float ss = e;
        ss += __shfl_xor(ss, 1);
        ss += __shfl_xor(ss, 2);
        ss += __shfl_xor(ss, 4);
        ss += __shfl_xor(ss, 8);
        return e * frcp(ss);
    };

    // h[lane] = b + sum_j x_j W[lane][j]; x broadcast via LDS; 4 accumulators
    auto matvec = [&](float xv) -> float {
        asm volatile("s_waitcnt lgkmcnt(0)" ::: "memory");  // WAR vs prior xb reads
        xb[lane] = xv;
        asm volatile("s_waitcnt lgkmcnt(0)" ::: "memory");  // write visible to wave
        float h0 = bval, h1 = 0.f, h2 = 0.f, h3 = 0.f;
        const float4* xv4 = (const float4*)xb;
        #pragma unroll
        for (int j = 0; j < 16; j += 4) {
            float4 w0 = W4[j],   x0 = xv4[j];
            float4 w1 = W4[j+1], x1 = xv4[j+1];
            float4 w2 = W4[j+2], x2 = xv4[j+2];
            float4 w3 = W4[j+3], x3 = xv4[j+3];
            h0 += w0.x*x0.x + w0.y*x0.y + w0.z*x0.z + w0.w*x0.w;
            h1 += w1.x*x1.x + w1.y*x1.y + w1.z*x1.z + w1.w*x1.w;
            h2 += w2.x*x2.x + w2.y*x2.y + w2.z*x2.z + w2.w*x2.w;
            h3 += w3.x*x3.x + w3.y*x3.y + w3.z*x3.z + w3.w*x3.w;
        }
        return (h0 + h1) + (h2 + h3);
    };

    // weighted gather: self + 16 neighbors, 2 accumulator chains
    auto gather = [&](int self, int ek, float w) -> float {
        float xa = emb_l[(size_t)(unsigned)self * DIM];
        float xc = 0.f;
        #pragma unroll
        for (int k = 0; k < KN; k += 2) {
            const int   e0 = __shfl(ek, k);
            const float f0 = __shfl(w,  k);
            const int   e1b = __shfl(ek, k + 1);
            const float f1 = __shfl(w,  k + 1);
            xa += f0 * emb_l[(size_t)(unsigned)e0  * DIM];
            xc += f1 * emb_l[(size_t)(unsigned)e1b * DIM];
        }
        return xa + xc;
    };

    // ---- phase A: this wave's 8 groups, adjacency prefetched 1 ahead ----
    int rk_n = 0, ek_n = 0;
    {
        const int g0 = __shfl(e1, half * GPW);
        if (lane < KN) {
            rk_n = adj_relation[(size_t)(unsigned)g0 * KN + lane];
            ek_n = adj_entity  [(size_t)(unsigned)g0 * KN + lane];
        }
    }
    #pragma unroll 1
    for (int mi = 0; mi < GPW; ++mi) {
        const int m  = half * GPW + mi;
        const int g  = __shfl(e1, m);
        const int rk = rk_n;
        const int ek = ek_n;
        if (mi + 1 < GPW) {
            const int gn = __shfl(e1, m + 1);
            if (lane < KN) {
                rk_n = adj_relation[(size_t)(unsigned)gn * KN + lane];
                ek_n = adj_entity  [(size_t)(unsigned)gn * KN + lane];
            }
        }
        const float w = softmax16(__shfl(acc, rk << 1));
        const float x = gather(g, ek, w);
        ev1[m * DIM + lane] = fmaxf(matvec(x), 0.f);
    }

    __syncthreads();
    if (half != 0) return;   // one tail wave per pair

    // ---- phase B: hop-0 layer 0 then layer 1 ----
    const float w0 = softmax16(__shfl(acc, rk0 << 1));
    const float x0 = gather(item, e1, w0);
    const float e0 = fmaxf(matvec(x0), 0.f);

    float xa = e0, xc = 0.f;
    #pragma unroll
    for (int k = 0; k < KN; k += 2) {
        xa += __shfl(w0, k)     * ev1[k * DIM + lane];
        xc += __shfl(w0, k + 1) * ev1[(k + 1) * DIM + lane];
    }
    const float itemf = tanhf(matvec(xa + xc));

    float d = user_emb[(size_t)user * DIM + lane] * itemf;
    d += __shfl_xor(d, 1);
    d += __shfl_xor(d, 2);
    d += __shfl_xor(d, 4);
    d += __shfl_xor(d, 8);
    d += __shfl_xor(d, 16);
    d += __shfl_xor(d, 32);
    if (lane == 0) out[p] = 1.f / (1.f + expf(-d));
}

extern "C" void kernel_launch(void* const* d_in, const int* in_sizes, int n_in,
                              void* d_out, int out_size, void* d_ws, size_t ws_size,
                              hipStream_t stream) {
    const int*   pairs        = (const int*)d_in[0];
    const int*   adj_entity   = (const int*)d_in[1];
    const int*   adj_relation = (const int*)d_in[2];
    const float* entity_emb   = (const float*)d_in[3];
    const float* relation_emb = (const float*)d_in[4];
    const float* user_emb     = (const float*)d_in[5];
    const float* W            = (const float*)d_in[6];
    const float* b            = (const float*)d_in[7];
    float* out = (float*)d_out;

    const int nPairs  = in_sizes[0] / 2;   // pairs is (B, 2)
    const int nBlocks = (nPairs + PPB - 1) / PPB;
    kgcn_kernel<<<nBlocks, 256, 0, stream>>>(pairs, adj_entity, adj_relation,
                                             entity_emb, relation_emb, user_emb,
                                             W, b, out, nPairs);
}

// Round 6
// 171.956 us; speedup vs baseline: 1.9435x; 1.3648x over previous
//
#include <hip/hip_runtime.h>
#include <math.h>

#define DIM  64
#define KN   16
#define NREL 32

__device__ __forceinline__ float frcp(float x) { return __builtin_amdgcn_rcpf(x); }

// ============================================================================
// Kernel 1: WE[e][d] = sum_j W[d][j] * entity_emb[e][j]   (= entity @ W^T)
// One wave computes 64 consecutive rows. Lane d keeps W row d in 16 float4
// regs (loaded once); the 64 input rows are staged to LDS coalesced, then
// broadcast-read (wave-uniform addresses). Stores are coalesced dwords.
// ============================================================================
__global__ __launch_bounds__(256, 2) void we_kernel(
    const float* __restrict__ entity_emb,
    const float* __restrict__ W,
    float* __restrict__ WE,
    int nRows)
{
    __shared__ float4 xs_s[4][64 * 16];   // 16 KB per wave
    const int tid  = threadIdx.x;
    const int wave = tid >> 6;
    const int lane = tid & 63;
    float4* xs = xs_s[wave];

    const int base = (blockIdx.x * 4 + wave) * 64;
    if (base >= nRows) return;

    // lane's W row (16 KB per wave total, L1-hot)
    float4 Wr[16];
    const float4* W4 = (const float4*)(W + lane * DIM);
    #pragma unroll
    for (int j = 0; j < 16; ++j) Wr[j] = W4[j];

    // stage 64 rows = 16 KB contiguous, fully coalesced; clamp OOB reads
    const float4* src = (const float4*)entity_emb;
    #pragma unroll
    for (int i = 0; i < 16; ++i) {
        const int idx = i * 64 + lane;                 // float4 idx in chunk
        const int row = base + (idx >> 4);
        const size_t g = (row < nRows) ? ((size_t)base * 16 + idx) : 0;
        xs[idx] = src[g];
    }
    asm volatile("s_waitcnt lgkmcnt(0)" ::: "memory");  // wave-local ds_writes done

    for (int r = 0; r < 64; ++r) {
        if (base + r >= nRows) break;
        float h0 = 0.f, h1 = 0.f, h2 = 0.f, h3 = 0.f;
        #pragma unroll
        for (int jc = 0; jc < 16; jc += 4) {
            float4 a = xs[r * 16 + jc + 0];   // wave-uniform addr: broadcast
            float4 b = xs[r * 16 + jc + 1];
            float4 c = xs[r * 16 + jc + 2];
            float4 d = xs[r * 16 + jc + 3];
            h0 += a.x*Wr[jc+0].x + a.y*Wr[jc+0].y + a.z*Wr[jc+0].z + a.w*Wr[jc+0].w;
            h1 += b.x*Wr[jc+1].x + b.y*Wr[jc+1].y + b.z*Wr[jc+1].z + b.w*Wr[jc+1].w;
            h2 += c.x*Wr[jc+2].x + c.y*Wr[jc+2].y + c.z*Wr[jc+2].z + c.w*Wr[jc+2].w;
            h3 += d.x*Wr[jc+3].x + d.y*Wr[jc+3].y + d.z*Wr[jc+3].z + d.w*Wr[jc+3].w;
        }
        WE[(size_t)(base + r) * DIM + lane] = (h0 + h1) + (h2 + h3);
    }
}

// ============================================================================
// Kernel 2: main. One wave per pair, zero barriers. All layer-0 "matvecs"
// are gathers from WE (linearity: W(e_g + sum w_k e_nk)+b = WE[g]+sum w_k
// WE[nk]+b, since softmax weights sum to 1 ReLU/tanh are the only
// non-linear points). Only ONE real matvec per pair (layer-1 after ReLU).
// ============================================================================
__global__ __launch_bounds__(256, 4) void kgcn_main(
    const int* __restrict__ pairs,
    const int* __restrict__ adjE,
    const int* __restrict__ adjR,
    const float* __restrict__ WE,
    const float* __restrict__ relation_emb,
    const float* __restrict__ user_emb,
    const float* __restrict__ W,
    const float* __restrict__ bias,
    float* __restrict__ out,
    int nPairs)
{
    __shared__ float ev1_s[4][KN * DIM];  // per-wave layer-0 outputs
    __shared__ float xb_s[4][DIM];        // per-wave matvec broadcast buffer

    const int tid  = threadIdx.x;
    const int wave = tid >> 6;
    const int lane = tid & 63;
    const int p    = blockIdx.x * 4 + wave;
    if (p >= nPairs) return;              // no barriers -> safe early-out

    float* ev1 = ev1_s[wave];
    float* xb  = xb_s[wave];

    const int user = pairs[2 * p + 0];
    const int item = pairs[2 * p + 1];

    const float bval   = bias[lane];
    const float uval   = user_emb[(size_t)user * DIM + lane];
    const float* WE_l  = WE + lane;

    // item adjacency row
    int rk0 = 0, e1 = 0;
    if (lane < KN) {
        rk0 = adjR[(size_t)item * KN + lane];
        e1  = adjE[(size_t)item * KN + lane];
    }

    // dot(u, rel_r) for all 32 relations: 2 lanes per relation
    float acc;
    {
        const int r = lane >> 1, hlf = lane & 1;
        const float4* rel4 = (const float4*)(relation_emb + r * DIM + hlf * 32);
        const float4* u4   = (const float4*)(user_emb + (size_t)user * DIM + hlf * 32);
        float a0 = 0.f, a1 = 0.f;
        #pragma unroll
        for (int j = 0; j < 8; j += 2) {
            float4 a = rel4[j],     b = u4[j];
            float4 c = rel4[j + 1], d = u4[j + 1];
            a0 += a.x*b.x + a.y*b.y + a.z*b.z + a.w*b.w;
            a1 += c.x*d.x + c.y*d.y + c.z*d.z + c.w*d.w;
        }
        acc = a0 + a1;
        acc += __shfl_xor(acc, 1);
    }

    // softmax within 16-lane subgroups (xor masks < 16 stay in-subgroup, so
    // 4 independent groups can be softmaxed in one call)
    auto softmax16 = [&](float s) -> float {
        float mx = s;
        mx = fmaxf(mx, __shfl_xor(mx, 1));
        mx = fmaxf(mx, __shfl_xor(mx, 2));
        mx = fmaxf(mx, __shfl_xor(mx, 4));
        mx = fmaxf(mx, __shfl_xor(mx, 8));
        float e = __expf(s - mx);
        float ss = e;
        ss += __shfl_xor(ss, 1);
        ss += __shfl_xor(ss, 2);
        ss += __shfl_xor(ss, 4);
        ss += __shfl_xor(ss, 8);
        return e * frcp(ss);
    };

    const float w0 = softmax16(__shfl(acc, rk0 << 1));

    // hop-1 adjacency packed 4 rows per register: slot c, subgroup m4 holds
    // group 4c+m4; lane = m4*16 + kk holds neighbor kk.
    const int m4 = lane >> 4, kk = lane & 15;
    int ekA[4]; float wA[4];
    #pragma unroll
    for (int c = 0; c < 4; ++c) {
        const int g  = __shfl(e1, 4 * c + m4);
        const int rk = adjR[(size_t)(unsigned)g * KN + kk];
        ekA[c]       = adjE[(size_t)(unsigned)g * KN + kk];
        wA[c] = softmax16(__shfl(acc, rk << 1));
    }

    // layer 0, hop 1: 16 groups, each = pure gather from WE (+bias, ReLU)
    #pragma unroll 2
    for (int m = 0; m < KN; ++m) {
        const int c   = m >> 2;
        const int sub = (m & 3) * 16;
        const int g   = __shfl(e1, m);
        float ha = WE_l[(size_t)(unsigned)g * DIM] + bval;
        float hb = 0.f;
        #pragma unroll
        for (int k = 0; k < KN; k += 2) {
            const int   ea = __shfl(ekA[c], sub + k);
            const float fa = __shfl(wA[c],  sub + k);
            const int   eb = __shfl(ekA[c], sub + k + 1);
            const float fb = __shfl(wA[c],  sub + k + 1);
            ha += fa * WE_l[(size_t)(unsigned)ea * DIM];
            hb += fb * WE_l[(size_t)(unsigned)eb * DIM];
        }
        ev1[m * DIM + lane] = fmaxf(ha + hb, 0.f);
    }

    // hop 0, layer 0: gather from WE with w0
    float ha = WE_l[(size_t)item * DIM] + bval;
    float hb = 0.f;
    #pragma unroll
    for (int k = 0; k < KN; k += 2) {
        const int   ea = __shfl(e1, k);
        const float fa = __shfl(w0, k);
        const int   eb = __shfl(e1, k + 1);
        const float fb = __shfl(w0, k + 1);
        ha += fa * WE_l[(size_t)(unsigned)ea * DIM];
        hb += fb * WE_l[(size_t)(unsigned)eb * DIM];
    }
    const float e0 = fmaxf(ha + hb, 0.f);

    // layer 1 aggregate: x1 = e0 + sum_m w0_m * ev1_m
    asm volatile("s_waitcnt lgkmcnt(0)" ::: "memory");  // ev1 writes done (wave-local)
    float xa = e0, xc = 0.f;
    #pragma unroll
    for (int k = 0; k < KN; k += 2) {
        xa += __shfl(w0, k)     * ev1[k * DIM + lane];
        xc += __shfl(w0, k + 1) * ev1[(k + 1) * DIM + lane];
    }
    const float x1 = xa + xc;

    // the ONE real matvec: h1 = W x1 + b, via LDS broadcast
    asm volatile("s_waitcnt lgkmcnt(0)" ::: "memory");
    xb[lane] = x1;
    asm volatile("s_waitcnt lgkmcnt(0)" ::: "memory");
    float h0 = bval, h1 = 0.f, h2 = 0.f, h3 = 0.f;
    {
        const float4* Wl  = (const float4*)(W + lane * DIM);
        const float4* xv4 = (const float4*)xb;
        #pragma unroll
        for (int j = 0; j < 16; j += 4) {
            float4 w0v = Wl[j],   x0v = xv4[j];
            float4 w1v = Wl[j+1], x1v = xv4[j+1];
            float4 w2v = Wl[j+2], x2v = xv4[j+2];
            float4 w3v = Wl[j+3], x3v = xv4[j+3];
            h0 += w0v.x*x0v.x + w0v.y*x0v.y + w0v.z*x0v.z + w0v.w*x0v.w;
            h1 += w1v.x*x1v.x + w1v.y*x1v.y + w1v.z*x1v.z + w1v.w*x1v.w;
            h2 += w2v.x*x2v.x + w2v.y*x2v.y + w2v.z*x2v.z + w2v.w*x2v.w;
            h3 += w3v.x*x3v.x + w3v.y*x3v.y + h3 * 0.f + w3v.z*x3v.z + w3v.w*x3v.w;
        }
    }
    const float itemf = tanhf((h0 + h1) + (h2 + h3));

    float d = uval * itemf;
    d += __shfl_xor(d, 1);
    d += __shfl_xor(d, 2);
    d += __shfl_xor(d, 4);
    d += __shfl_xor(d, 8);
    d += __shfl_xor(d, 16);
    d += __shfl_xor(d, 32);
    if (lane == 0) out[p] = 1.f / (1.f + expf(-d));
}

// ============================================================================
// Fallback (verified R5 kernel) in case ws_size < WE table size.
// ============================================================================
__global__ __launch_bounds__(256, 4) void kgcn_fallback(
    const int* __restrict__ pairs, const int* __restrict__ adj_entity,
    const int* __restrict__ adj_relation, const float* __restrict__ entity_emb,
    const float* __restrict__ relation_emb, const float* __restrict__ user_emb,
    const float* __restrict__ W, const float* __restrict__ bias,
    float* __restrict__ out, int nPairs)
{
    __shared__ float ev1_s[2][KN * DIM];
    __shared__ float xb_s[4][DIM];
    const int tid = threadIdx.x, wave = tid >> 6, lane = tid & 63;
    const int q = wave >> 1, half = wave & 1;
    int p = blockIdx.x * 2 + q;
    if (p >= nPairs) p = nPairs - 1;
    float* ev1 = ev1_s[q]; float* xb = xb_s[wave];
    const int user = pairs[2 * p + 0], item = pairs[2 * p + 1];
    const float bval = bias[lane];
    const float* emb_l = entity_emb + lane;
    const float4* W4 = (const float4*)(W + lane * DIM);
    int rk0 = 0, e1 = 0;
    if (lane < KN) {
        rk0 = adj_relation[(size_t)item * KN + lane];
        e1  = adj_entity[(size_t)item * KN + lane];
    }
    float acc;
    {
        const int r = lane >> 1, hlf = lane & 1;
        const float4* rel4 = (const float4*)(relation_emb + r * DIM + hlf * 32);
        const float4* u4 = (const float4*)(user_emb + (size_t)user * DIM + hlf * 32);
        float a0 = 0.f, a1 = 0.f;
        #pragma unroll
        for (int j = 0; j < 8; j += 2) {
            float4 a = rel4[j], b = u4[j], c = rel4[j+1], d = u4[j+1];
            a0 += a.x*b.x + a.y*b.y + a.z*b.z + a.w*b.w;
            a1 += c.x*d.x + c.y*d.y + c.z*d.z + c.w*d.w;
        }
        acc = a0 + a1; acc += __shfl_xor(acc, 1);
    }
    auto softmax16 = [&](float s) -> float {
        float mx = s;
        mx = fmaxf(mx, __shfl_xor(mx, 1)); mx = fmaxf(mx, __shfl_xor(mx, 2));
        mx = fmaxf(mx, __shfl_xor(mx, 4)); mx = fmaxf(mx, __shfl_xor(mx, 8));
        float e = __expf(s - mx);
        float ss = e;
        ss += __shfl_xor(ss, 1); ss += __shfl_xor(ss, 2);
        ss += __shfl_xor(ss, 4); ss += __shfl_xor(ss, 8);
        return e * frcp(ss);
    };
    auto matvec = [&](float xv) -> float {
        asm volatile("s_waitcnt lgkmcnt(0)" ::: "memory");
        xb[lane] = xv;
        asm volatile("s_waitcnt lgkmcnt(0)" ::: "memory");
        float h0 = bval, h1 = 0.f, h2 = 0.f, h3 = 0.f;
        const float4* xv4 = (const float4*)xb;
        #pragma unroll
        for (int j = 0; j < 16; j += 4) {
            float4 w0 = W4[j], x0 = xv4[j], w1 = W4[j+1], x1 = xv4[j+1];
            float4 w2 = W4[j+2], x2 = xv4[j+2], w3 = W4[j+3], x3 = xv4[j+3];
            h0 += w0.x*x0.x + w0.y*x0.y + w0.z*x0.z + w0.w*x0.w;
            h1 += w1.x*x1.x + w1.y*x1.y + w1.z*x1.z + w1.w*x1.w;
            h2 += w2.x*x2.x + w2.y*x2.y + w2.z*x2.z + w2.w*x2.w;
            h3 += w3.x*x3.x + w3.y*x3.y + w3.z*x3.z + w3.w*x3.w;
        }
        return (h0 + h1) + (h2 + h3);
    };
    auto gather = [&](int self, int ek, float w) -> float {
        float xa = emb_l[(size_t)(unsigned)self * DIM], xc = 0.f;
        #pragma unroll
        for (int k = 0; k < KN; k += 2) {
            const int e0i = __shfl(ek, k); const float f0 = __shfl(w, k);
            const int e1i = __shfl(ek, k + 1); const float f1 = __shfl(w, k + 1);
            xa += f0 * emb_l[(size_t)(unsigned)e0i * DIM];
            xc += f1 * emb_l[(size_t)(unsigned)e1i * DIM];
        }
        return xa + xc;
    };
    int rk_n = 0, ek_n = 0;
    {
        const int g0 = __shfl(e1, half * 8);
        if (lane < KN) {
            rk_n = adj_relation[(size_t)(unsigned)g0 * KN + lane];
            ek_n = adj_entity[(size_t)(unsigned)g0 * KN + lane];
        }
    }
    #pragma unroll 1
    for (int mi = 0; mi < 8; ++mi) {
        const int m = half * 8 + mi;
        const int g = __shfl(e1, m);
        const int rk = rk_n, ek = ek_n;
        if (mi + 1 < 8) {
            const int gn = __shfl(e1, m + 1);
            if (lane < KN) {
                rk_n = adj_relation[(size_t)(unsigned)gn * KN + lane];
                ek_n = adj_entity[(size_t)(unsigned)gn * KN + lane];
            }
        }
        const float w = softmax16(__shfl(acc, rk << 1));
        const float x = gather(g, ek, w);
        ev1[m * DIM + lane] = fmaxf(matvec(x), 0.f);
    }
    __syncthreads();
    if (half != 0) return;
    const float w0 = softmax16(__shfl(acc, rk0 << 1));
    const float x0 = gather(item, e1, w0);
    const float e0 = fmaxf(matvec(x0), 0.f);
    float xa = e0, xc = 0.f;
    #pragma unroll
    for (int k = 0; k < KN; k += 2) {
        xa += __shfl(w0, k) * ev1[k * DIM + lane];
        xc += __shfl(w0, k + 1) * ev1[(k + 1) * DIM + lane];
    }
    const float itemf = tanhf(matvec(xa + xc));
    float d = user_emb[(size_t)user * DIM + lane] * itemf;
    d += __shfl_xor(d, 1); d += __shfl_xor(d, 2); d += __shfl_xor(d, 4);
    d += __shfl_xor(d, 8); d += __shfl_xor(d, 16); d += __shfl_xor(d, 32);
    if (lane == 0) out[p] = 1.f / (1.f + expf(-d));
}

extern "C" void kernel_launch(void* const* d_in, const int* in_sizes, int n_in,
                              void* d_out, int out_size, void* d_ws, size_t ws_size,
                              hipStream_t stream) {
    const int*   pairs        = (const int*)d_in[0];
    const int*   adj_entity   = (const int*)d_in[1];
    const int*   adj_relation = (const int*)d_in[2];
    const float* entity_emb   = (const float*)d_in[3];
    const float* relation_emb = (const float*)d_in[4];
    const float* user_emb     = (const float*)d_in[5];
    const float* W            = (const float*)d_in[6];
    const float* b            = (const float*)d_in[7];
    float* out = (float*)d_out;

    const int nPairs = in_sizes[0] / 2;          // pairs is (B, 2)
    const int nEnt   = in_sizes[3] / DIM;        // entity count
    const size_t weBytes = (size_t)in_sizes[3] * sizeof(float);

    if (ws_size >= weBytes) {
        float* WE = (float*)d_ws;
        const int preBlocks = (nEnt + 255) / 256;   // 64 rows/wave * 4 waves
        we_kernel<<<preBlocks, 256, 0, stream>>>(entity_emb, W, WE, nEnt);
        const int mainBlocks = (nPairs + 3) / 4;
        kgcn_main<<<mainBlocks, 256, 0, stream>>>(pairs, adj_entity, adj_relation,
                                                  WE, relation_emb, user_emb,
                                                  W, b, out, nPairs);
    } else {
        const int nBlocks = (nPairs + 1) / 2;
        kgcn_fallback<<<nBlocks, 256, 0, stream>>>(pairs, adj_entity, adj_relation,
                                                   entity_emb, relation_emb, user_emb,
                                                   W, b, out, nPairs);
    }
}

// Round 7
// 154.784 us; speedup vs baseline: 2.1592x; 1.1109x over previous
//
#include <hip/hip_runtime.h>
#include <hip/hip_bf16.h>
#include <math.h>

#define DIM  64
#define KN   16
#define NREL 32

__device__ __forceinline__ float frcp(float x) { return __builtin_amdgcn_rcpf(x); }

__device__ __forceinline__ unsigned short f2bf(float f) {
    unsigned u = __float_as_uint(f);
    u = (u + 0x7fffu + ((u >> 16) & 1u)) >> 16;   // RNE
    return (unsigned short)u;
}
__device__ __forceinline__ float bf2f(unsigned short b) {
    return __uint_as_float((unsigned)b << 16);
}

// ============================================================================
// Kernel 1: WEb[e][d] = bf16( sum_j W[d][j] * entity_emb[e][j] )
// 8 rows per wave, wave-private LDS staging, zero barriers. 12500 waves.
// ============================================================================
__global__ __launch_bounds__(256, 4) void we_kernel(
    const float* __restrict__ entity_emb,
    const float* __restrict__ W,
    unsigned short* __restrict__ WEb,
    int nRows)
{
    __shared__ float4 xs_s[4][8 * 16];   // 2 KB per wave
    const int tid  = threadIdx.x;
    const int wave = tid >> 6;
    const int lane = tid & 63;
    float4* xs = xs_s[wave];

    const int base = (blockIdx.x * 4 + wave) * 8;
    if (base >= nRows) return;

    // lane's W row in 16 float4 regs (L1-hot after first block)
    float4 Wr[16];
    const float4* W4 = (const float4*)(W + lane * DIM);
    #pragma unroll
    for (int j = 0; j < 16; ++j) Wr[j] = W4[j];

    // stage 8 rows = 2 KB, coalesced 16B/lane; clamp OOB to row 0
    const float4* src = (const float4*)entity_emb;
    #pragma unroll
    for (int i = 0; i < 2; ++i) {
        const int idx = i * 64 + lane;                // float4 idx within chunk
        const int row = base + (idx >> 4);
        const size_t g = (row < nRows) ? ((size_t)base * 16 + idx) : 0;
        xs[idx] = src[g];
    }
    asm volatile("s_waitcnt lgkmcnt(0)" ::: "memory");   // wave-local ds_writes

    #pragma unroll
    for (int r = 0; r < 8; ++r) {
        const int row = base + r;
        if (row >= nRows) break;
        float h0 = 0.f, h1 = 0.f, h2 = 0.f, h3 = 0.f;
        #pragma unroll
        for (int jc = 0; jc < 16; jc += 4) {
            float4 a = xs[r * 16 + jc + 0];   // wave-uniform addr: broadcast
            float4 b = xs[r * 16 + jc + 1];
            float4 c = xs[r * 16 + jc + 2];
            float4 d = xs[r * 16 + jc + 3];
            h0 += a.x*Wr[jc+0].x + a.y*Wr[jc+0].y + a.z*Wr[jc+0].z + a.w*Wr[jc+0].w;
            h1 += b.x*Wr[jc+1].x + b.y*Wr[jc+1].y + b.z*Wr[jc+1].z + b.w*Wr[jc+1].w;
            h2 += c.x*Wr[jc+2].x + c.y*Wr[jc+2].y + c.z*Wr[jc+2].z + c.w*Wr[jc+2].w;
            h3 += d.x*Wr[jc+3].x + d.y*Wr[jc+3].y + d.z*Wr[jc+3].z + d.w*Wr[jc+3].w;
        }
        WEb[(size_t)row * DIM + lane] = f2bf((h0 + h1) + (h2 + h3));
    }
}

// ============================================================================
// Kernel 2: main. One wave per pair, zero barriers. Layer-0 matvecs folded
// into the gather via linearity; gathers read the bf16 WE table (128B rows:
// half the L2-miss traffic, 2x the per-XCD L2 coverage vs fp32).
// ============================================================================
__global__ __launch_bounds__(256, 4) void kgcn_main(
    const int* __restrict__ pairs,
    const int* __restrict__ adjE,
    const int* __restrict__ adjR,
    const unsigned short* __restrict__ WEb,
    const float* __restrict__ relation_emb,
    const float* __restrict__ user_emb,
    const float* __restrict__ W,
    const float* __restrict__ bias,
    float* __restrict__ out,
    int nPairs)
{
    __shared__ float ev1_s[4][KN * DIM];  // per-wave layer-0 outputs
    __shared__ float xb_s[4][DIM];        // per-wave matvec broadcast buffer

    const int tid  = threadIdx.x;
    const int wave = tid >> 6;
    const int lane = tid & 63;
    const int p    = blockIdx.x * 4 + wave;
    if (p >= nPairs) return;              // no barriers -> safe early-out

    float* ev1 = ev1_s[wave];
    float* xb  = xb_s[wave];

    const int user = pairs[2 * p + 0];
    const int item = pairs[2 * p + 1];

    const float bval = bias[lane];
    const float uval = user_emb[(size_t)user * DIM + lane];
    const unsigned short* WE_l = WEb + lane;

    // item adjacency row
    int rk0 = 0, e1 = 0;
    if (lane < KN) {
        rk0 = adjR[(size_t)item * KN + lane];
        e1  = adjE[(size_t)item * KN + lane];
    }

    // dot(u, rel_r) for all 32 relations: 2 lanes per relation
    float acc;
    {
        const int r = lane >> 1, hlf = lane & 1;
        const float4* rel4 = (const float4*)(relation_emb + r * DIM + hlf * 32);
        const float4* u4   = (const float4*)(user_emb + (size_t)user * DIM + hlf * 32);
        float a0 = 0.f, a1 = 0.f;
        #pragma unroll
        for (int j = 0; j < 8; j += 2) {
            float4 a = rel4[j],     b = u4[j];
            float4 c = rel4[j + 1], d = u4[j + 1];
            a0 += a.x*b.x + a.y*b.y + a.z*b.z + a.w*b.w;
            a1 += c.x*d.x + c.y*d.y + c.z*d.z + c.w*d.w;
        }
        acc = a0 + a1;
        acc += __shfl_xor(acc, 1);
    }

    // softmax within 16-lane subgroups (4 independent groups per call)
    auto softmax16 = [&](float s) -> float {
        float mx = s;
        mx = fmaxf(mx, __shfl_xor(mx, 1));
        mx = fmaxf(mx, __shfl_xor(mx, 2));
        mx = fmaxf(mx, __shfl_xor(mx, 4));
        mx = fmaxf(mx, __shfl_xor(mx, 8));
        float e = __expf(s - mx);
        float ss = e;
        ss += __shfl_xor(ss, 1);
        ss += __shfl_xor(ss, 2);
        ss += __shfl_xor(ss, 4);
        ss += __shfl_xor(ss, 8);
        return e * frcp(ss);
    };

    const float w0 = softmax16(__shfl(acc, rk0 << 1));

    // hop-1 adjacency packed 4 rows per register: slot c, subgroup m4 holds
    // group 4c+m4; lane = m4*16 + kk holds neighbor kk.
    const int m4 = lane >> 4, kk = lane & 15;
    int ekA[4]; float wA[4];
    #pragma unroll
    for (int c = 0; c < 4; ++c) {
        const int g  = __shfl(e1, 4 * c + m4);
        const int rk = adjR[(size_t)(unsigned)g * KN + kk];
        ekA[c]       = adjE[(size_t)(unsigned)g * KN + kk];
        wA[c] = softmax16(__shfl(acc, rk << 1));
    }

    // layer 0, hop 1: 16 groups, each = pure gather from WEb (+bias, ReLU)
    #pragma unroll 2
    for (int m = 0; m < KN; ++m) {
        const int c   = m >> 2;
        const int sub = (m & 3) * 16;
        const int g   = __shfl(e1, m);
        float ha = bf2f(WE_l[(size_t)(unsigned)g * DIM]) + bval;
        float hb = 0.f;
        #pragma unroll
        for (int k = 0; k < KN; k += 2) {
            const int   ea = __shfl(ekA[c], sub + k);
            const float fa = __shfl(wA[c],  sub + k);
            const int   eb = __shfl(ekA[c], sub + k + 1);
            const float fb = __shfl(wA[c],  sub + k + 1);
            ha += fa * bf2f(WE_l[(size_t)(unsigned)ea * DIM]);
            hb += fb * bf2f(WE_l[(size_t)(unsigned)eb * DIM]);
        }
        ev1[m * DIM + lane] = fmaxf(ha + hb, 0.f);
    }

    // hop 0, layer 0: gather from WEb with w0
    float ha = bf2f(WE_l[(size_t)item * DIM]) + bval;
    float hb = 0.f;
    #pragma unroll
    for (int k = 0; k < KN; k += 2) {
        const int   ea = __shfl(e1, k);
        const float fa = __shfl(w0, k);
        const int   eb = __shfl(e1, k + 1);
        const float fb = __shfl(w0, k + 1);
        ha += fa * bf2f(WE_l[(size_t)(unsigned)ea * DIM]);
        hb += fb * bf2f(WE_l[(size_t)(unsigned)eb * DIM]);
    }
    const float e0 = fmaxf(ha + hb, 0.f);

    // layer 1 aggregate: x1 = e0 + sum_m w0_m * ev1_m
    asm volatile("s_waitcnt lgkmcnt(0)" ::: "memory");  // ev1 writes done (wave-local)
    float xa = e0, xc = 0.f;
    #pragma unroll
    for (int k = 0; k < KN; k += 2) {
        xa += __shfl(w0, k)     * ev1[k * DIM + lane];
        xc += __shfl(w0, k + 1) * ev1[(k + 1) * DIM + lane];
    }
    const float x1 = xa + xc;

    // the ONE real matvec: h1 = W x1 + b, via LDS broadcast
    asm volatile("s_waitcnt lgkmcnt(0)" ::: "memory");
    xb[lane] = x1;
    asm volatile("s_waitcnt lgkmcnt(0)" ::: "memory");
    float h0 = bval, h1 = 0.f, h2 = 0.f, h3 = 0.f;
    {
        const float4* Wl  = (const float4*)(W + lane * DIM);
        const float4* xv4 = (const float4*)xb;
        #pragma unroll
        for (int j = 0; j < 16; j += 4) {
            float4 w0v = Wl[j],   x0v = xv4[j];
            float4 w1v = Wl[j+1], x1v = xv4[j+1];
            float4 w2v = Wl[j+2], x2v = xv4[j+2];
            float4 w3v = Wl[j+3], x3v = xv4[j+3];
            h0 += w0v.x*x0v.x + w0v.y*x0v.y + w0v.z*x0v.z + w0v.w*x0v.w;
            h1 += w1v.x*x1v.x + w1v.y*x1v.y + w1v.z*x1v.z + w1v.w*x1v.w;
            h2 += w2v.x*x2v.x + w2v.y*x2v.y + w2v.z*x2v.z + w2v.w*x2v.w;
            h3 += w3v.x*x3v.x + w3v.y*x3v.y + w3v.z*x3v.z + w3v.w*x3v.w;
        }
    }
    const float itemf = tanhf((h0 + h1) + (h2 + h3));

    float d = uval * itemf;
    d += __shfl_xor(d, 1);
    d += __shfl_xor(d, 2);
    d += __shfl_xor(d, 4);
    d += __shfl_xor(d, 8);
    d += __shfl_xor(d, 16);
    d += __shfl_xor(d, 32);
    if (lane == 0) out[p] = 1.f / (1.f + expf(-d));
}

// ============================================================================
// Fallback (verified R5 kernel) in case ws_size < WE table size.
// ============================================================================
__global__ __launch_bounds__(256, 4) void kgcn_fallback(
    const int* __restrict__ pairs, const int* __restrict__ adj_entity,
    const int* __restrict__ adj_relation, const float* __restrict__ entity_emb,
    const float* __restrict__ relation_emb, const float* __restrict__ user_emb,
    const float* __restrict__ W, const float* __restrict__ bias,
    float* __restrict__ out, int nPairs)
{
    __shared__ float ev1_s[2][KN * DIM];
    __shared__ float xb_s[4][DIM];
    const int tid = threadIdx.x, wave = tid >> 6, lane = tid & 63;
    const int q = wave >> 1, half = wave & 1;
    int p = blockIdx.x * 2 + q;
    if (p >= nPairs) p = nPairs - 1;
    float* ev1 = ev1_s[q]; float* xb = xb_s[wave];
    const int user = pairs[2 * p + 0], item = pairs[2 * p + 1];
    const float bval = bias[lane];
    const float* emb_l = entity_emb + lane;
    const float4* W4 = (const float4*)(W + lane * DIM);
    int rk0 = 0, e1 = 0;
    if (lane < KN) {
        rk0 = adj_relation[(size_t)item * KN + lane];
        e1  = adj_entity[(size_t)item * KN + lane];
    }
    float acc;
    {
        const int r = lane >> 1, hlf = lane & 1;
        const float4* rel4 = (const float4*)(relation_emb + r * DIM + hlf * 32);
        const float4* u4 = (const float4*)(user_emb + (size_t)user * DIM + hlf * 32);
        float a0 = 0.f, a1 = 0.f;
        #pragma unroll
        for (int j = 0; j < 8; j += 2) {
            float4 a = rel4[j], b = u4[j], c = rel4[j+1], d = u4[j+1];
            a0 += a.x*b.x + a.y*b.y + a.z*b.z + a.w*b.w;
            a1 += c.x*d.x + c.y*d.y + c.z*d.z + c.w*d.w;
        }
        acc = a0 + a1; acc += __shfl_xor(acc, 1);
    }
    auto softmax16 = [&](float s) -> float {
        float mx = s;
        mx = fmaxf(mx, __shfl_xor(mx, 1)); mx = fmaxf(mx, __shfl_xor(mx, 2));
        mx = fmaxf(mx, __shfl_xor(mx, 4)); mx = fmaxf(mx, __shfl_xor(mx, 8));
        float e = __expf(s - mx);
        float ss = e;
        ss += __shfl_xor(ss, 1); ss += __shfl_xor(ss, 2);
        ss += __shfl_xor(ss, 4); ss += __shfl_xor(ss, 8);
        return e * frcp(ss);
    };
    auto matvec = [&](float xv) -> float {
        asm volatile("s_waitcnt lgkmcnt(0)" ::: "memory");
        xb[lane] = xv;
        asm volatile("s_waitcnt lgkmcnt(0)" ::: "memory");
        float h0 = bval, h1 = 0.f, h2 = 0.f, h3 = 0.f;
        const float4* xv4 = (const float4*)xb;
        #pragma unroll
        for (int j = 0; j < 16; j += 4) {
            float4 w0 = W4[j], x0 = xv4[j], w1 = W4[j+1], x1 = xv4[j+1];
            float4 w2 = W4[j+2], x2 = xv4[j+2], w3 = W4[j+3], x3 = xv4[j+3];
            h0 += w0.x*x0.x + w0.y*x0.y + w0.z*x0.z + w0.w*x0.w;
            h1 += w1.x*x1.x + w1.y*x1.y + w1.z*x1.z + w1.w*x1.w;
            h2 += w2.x*x2.x + w2.y*x2.y + w2.z*x2.z + w2.w*x2.w;
            h3 += w3.x*x3.x + w3.y*x3.y + w3.z*x3.z + w3.w*x3.w;
        }
        return (h0 + h1) + (h2 + h3);
    };
    auto gather = [&](int self, int ek, float w) -> float {
        float xa = emb_l[(size_t)(unsigned)self * DIM], xc = 0.f;
        #pragma unroll
        for (int k = 0; k < KN; k += 2) {
            const int e0i = __shfl(ek, k); const float f0 = __shfl(w, k);
            const int e1i = __shfl(ek, k + 1); const float f1 = __shfl(w, k + 1);
            xa += f0 * emb_l[(size_t)(unsigned)e0i * DIM];
            xc += f1 * emb_l[(size_t)(unsigned)e1i * DIM];
        }
        return xa + xc;
    };
    int rk_n = 0, ek_n = 0;
    {
        const int g0 = __shfl(e1, half * 8);
        if (lane < KN) {
            rk_n = adj_relation[(size_t)(unsigned)g0 * KN + lane];
            ek_n = adj_entity[(size_t)(unsigned)g0 * KN + lane];
        }
    }
    #pragma unroll 1
    for (int mi = 0; mi < 8; ++mi) {
        const int m = half * 8 + mi;
        const int g = __shfl(e1, m);
        const int rk = rk_n, ek = ek_n;
        if (mi + 1 < 8) {
            const int gn = __shfl(e1, m + 1);
            if (lane < KN) {
                rk_n = adj_relation[(size_t)(unsigned)gn * KN + lane];
                ek_n = adj_entity[(size_t)(unsigned)gn * KN + lane];
            }
        }
        const float w = softmax16(__shfl(acc, rk << 1));
        const float x = gather(g, ek, w);
        ev1[m * DIM + lane] = fmaxf(matvec(x), 0.f);
    }
    __syncthreads();
    if (half != 0) return;
    const float w0 = softmax16(__shfl(acc, rk0 << 1));
    const float x0 = gather(item, e1, w0);
    const float e0 = fmaxf(matvec(x0), 0.f);
    float xa = e0, xc = 0.f;
    #pragma unroll
    for (int k = 0; k < KN; k += 2) {
        xa += __shfl(w0, k) * ev1[k * DIM + lane];
        xc += __shfl(w0, k + 1) * ev1[(k + 1) * DIM + lane];
    }
    const float itemf = tanhf(matvec(xa + xc));
    float d = user_emb[(size_t)user * DIM + lane] * itemf;
    d += __shfl_xor(d, 1); d += __shfl_xor(d, 2); d += __shfl_xor(d, 4);
    d += __shfl_xor(d, 8); d += __shfl_xor(d, 16); d += __shfl_xor(d, 32);
    if (lane == 0) out[p] = 1.f / (1.f + expf(-d));
}

extern "C" void kernel_launch(void* const* d_in, const int* in_sizes, int n_in,
                              void* d_out, int out_size, void* d_ws, size_t ws_size,
                              hipStream_t stream) {
    const int*   pairs        = (const int*)d_in[0];
    const int*   adj_entity   = (const int*)d_in[1];
    const int*   adj_relation = (const int*)d_in[2];
    const float* entity_emb   = (const float*)d_in[3];
    const float* relation_emb = (const float*)d_in[4];
    const float* user_emb     = (const float*)d_in[5];
    const float* W            = (const float*)d_in[6];
    const float* b            = (const float*)d_in[7];
    float* out = (float*)d_out;

    const int nPairs = in_sizes[0] / 2;          // pairs is (B, 2)
    const int nEnt   = in_sizes[3] / DIM;        // entity count
    const size_t weBytes = (size_t)in_sizes[3] * sizeof(unsigned short);

    if (ws_size >= weBytes) {
        unsigned short* WEb = (unsigned short*)d_ws;
        const int preBlocks = (nEnt + 8 * 4 - 1) / (8 * 4);   // 8 rows/wave
        we_kernel<<<preBlocks, 256, 0, stream>>>(entity_emb, W, WEb, nEnt);
        const int mainBlocks = (nPairs + 3) / 4;
        kgcn_main<<<mainBlocks, 256, 0, stream>>>(pairs, adj_entity, adj_relation,
                                                  WEb, relation_emb, user_emb,
                                                  W, b, out, nPairs);
    } else {
        const int nBlocks = (nPairs + 1) / 2;
        kgcn_fallback<<<nBlocks, 256, 0, stream>>>(pairs, adj_entity, adj_relation,
                                                   entity_emb, relation_emb, user_emb,
                                                   W, b, out, nPairs);
    }
}